// Round 12
// baseline (281.682 us; speedup 1.0000x reference)
//
#include <hip/hip_runtime.h>
#include <math.h>

// Capsule routing, fully fused to ONE dispatch. B=64, I=1024, O=1024 fp32.
//
// Math: routing collapses to c_k = softmax_o(u*w*vsum) -> no [B,I,O] tensor.
// R7-R11 lesson: stage/gemm/reduce kernels are each near their latency
// floor (~20/8/4 us); the dominant remaining cost is ~9-10 us of gap per
// dispatch x 7 dispatches. R12: single kernel, 6 phases, 5 hand-rolled
// device-scope grid barriers (fence + atomicAdd arrival + acquire spin).
// Residency-safe without cooperative API: 256 blocks x 1024 thr; VGPR<=64
// -> capacity 512; VGPR in (64,128] -> exactly 256. Barrier counters are
// zeroed by hipMemsetAsync before launch (graph-capture-proven R1/R2).

#define BB 64
#define II 1024
#define OO 1024
#define EPSF 1e-5f
#define LOG2E 1.44269504088896340736f
#define NBLK 256          // mega-kernel grid
#define MIBLKS 64         // partial slices in mega path
#define MIPB (II / MIBLKS)

__device__ __forceinline__ float wave_sum(float v) {
    #pragma unroll
    for (int off = 32; off > 0; off >>= 1)
        v += __shfl_xor(v, off, 64);
    return v;
}
__device__ __forceinline__ float rfl(float x) {  // force SGPR broadcast
    return __int_as_float(__builtin_amdgcn_readfirstlane(__float_as_int(x)));
}

// Device-scope grid barrier. Release: __threadfence (write-back) + arrival
// add; acquire: spin on agent-scope acquire load (invalidates L1/L2 line).
__device__ __forceinline__ void gbar(int* c) {
    __syncthreads();
    if (threadIdx.x == 0) {
        __threadfence();
        __hip_atomic_fetch_add(c, 1, __ATOMIC_RELAXED, __HIP_MEMORY_SCOPE_AGENT);
        while (__hip_atomic_load(c, __ATOMIC_ACQUIRE,
                                 __HIP_MEMORY_SCOPE_AGENT) < NBLK) { }
    }
    __syncthreads();
}

// ---- per-wave phase bodies (R7-proven), templated on i's-per-wave ----

template<int IPB>
__device__ __forceinline__ void gemm_wave(
    const float* __restrict__ u, const float* __restrict__ w,
    float* __restrict__ part, int b, int iblk, int lane)
{
    const float4* w4 = (const float4*)w;
    float ar[16];
    #pragma unroll
    for (int k = 0; k < 16; k++) ar[k] = 0.f;
    const int i0 = iblk * IPB;
    #pragma unroll 2
    for (int ii = 0; ii < IPB; ii++) {
        const int i = i0 + ii;
        const float ub = rfl(u[b * II + i]);
        #pragma unroll
        for (int j = 0; j < 4; j++) {
            float4 t = w4[i * 256 + j * 64 + lane];
            ar[j*4+0] = fmaf(ub, t.x, ar[j*4+0]);
            ar[j*4+1] = fmaf(ub, t.y, ar[j*4+1]);
            ar[j*4+2] = fmaf(ub, t.z, ar[j*4+2]);
            ar[j*4+3] = fmaf(ub, t.w, ar[j*4+3]);
        }
    }
    float4* dst = (float4*)(part + ((size_t)iblk * BB + b) * OO);
    #pragma unroll
    for (int j = 0; j < 4; j++) {
        float4 o;
        o.x = ar[j*4+0]; o.y = ar[j*4+1]; o.z = ar[j*4+2]; o.w = ar[j*4+3];
        dst[j * 64 + lane] = o;
    }
}

template<int IPB>
__device__ __forceinline__ void stage_wave(
    const float* __restrict__ u, const float* __restrict__ w,
    const float* __restrict__ v, float* __restrict__ part,
    int b, int iblk, int lane)
{
    constexpr int NG = IPB / 8;
    const float4* w4 = (const float4*)w;
    const float4* v4 = (const float4*)(v + b * OO);

    float vv[16];
    #pragma unroll
    for (int j = 0; j < 4; j++) {
        float4 a = v4[j * 64 + lane];
        vv[j*4+0]=a.x*LOG2E; vv[j*4+1]=a.y*LOG2E;
        vv[j*4+2]=a.z*LOG2E; vv[j*4+3]=a.w*LOG2E;
    }
    float ar[16];
    #pragma unroll
    for (int k = 0; k < 16; k++) ar[k] = 0.f;

    const int i0 = iblk * IPB;
    #pragma unroll 1
    for (int g = 0; g < NG; g++) {
        const int ib = i0 + g * 8;
        float us[8];
        #pragma unroll
        for (int ii = 0; ii < 8; ii++)
            us[ii] = rfl(u[b * II + ib + ii]);

        // pass A: per-lane partial denominators
        float sA[8];
        #pragma unroll 2
        for (int ii = 0; ii < 8; ii++) {
            const int i = ib + ii;
            float a0 = 0.f;
            #pragma unroll
            for (int j = 0; j < 4; j++) {
                float4 t = w4[i * 256 + j * 64 + lane];
                a0 += __builtin_amdgcn_exp2f((t.x * vv[j*4+0]) * us[ii])
                    + __builtin_amdgcn_exp2f((t.y * vv[j*4+1]) * us[ii])
                    + __builtin_amdgcn_exp2f((t.z * vv[j*4+2]) * us[ii])
                    + __builtin_amdgcn_exp2f((t.w * vv[j*4+3]) * us[ii]);
            }
            sA[ii] = a0;
        }
        // batched butterfly
        #pragma unroll
        for (int off = 32; off > 0; off >>= 1) {
            #pragma unroll
            for (int ii = 0; ii < 8; ii++)
                sA[ii] += __shfl_xor(sA[ii], off, 64);
        }
        float qs[8];
        #pragma unroll
        for (int ii = 0; ii < 8; ii++)
            qs[ii] = rfl(us[ii] * __builtin_amdgcn_rcpf(sA[ii]));

        // pass B: re-stream (L1-hot) rows, accumulate
        #pragma unroll 2
        for (int ii = 0; ii < 8; ii++) {
            const int i = ib + ii;
            #pragma unroll
            for (int j = 0; j < 4; j++) {
                float4 t = w4[i * 256 + j * 64 + lane];
                float p;
                p = __builtin_amdgcn_exp2f((t.x * vv[j*4+0]) * us[ii]);
                ar[j*4+0] = fmaf(t.x * p, qs[ii], ar[j*4+0]);
                p = __builtin_amdgcn_exp2f((t.y * vv[j*4+1]) * us[ii]);
                ar[j*4+1] = fmaf(t.y * p, qs[ii], ar[j*4+1]);
                p = __builtin_amdgcn_exp2f((t.z * vv[j*4+2]) * us[ii]);
                ar[j*4+2] = fmaf(t.z * p, qs[ii], ar[j*4+2]);
                p = __builtin_amdgcn_exp2f((t.w * vv[j*4+3]) * us[ii]);
                ar[j*4+3] = fmaf(t.w * p, qs[ii], ar[j*4+3]);
            }
        }
    }
    float4* dst = (float4*)(part + ((size_t)iblk * BB + b) * OO);
    #pragma unroll
    for (int j = 0; j < 4; j++) {
        float4 o;
        o.x = ar[j*4+0]; o.y = ar[j*4+1]; o.z = ar[j*4+2]; o.w = ar[j*4+3];
        dst[j * 64 + lane] = o;
    }
}

// 1024-thread reduce+squash for row b (R7-proven). mode 0: vbuf=v,
// 1: vbuf+=v, 2: out=v. redq = 16KB shared scratch.
__device__ __forceinline__ void reduce_block(
    const float* __restrict__ part, const float* __restrict__ bias,
    float* __restrict__ vbuf, float* __restrict__ out,
    float scale, int mode, int nblk, int b, float4* redq, float* red2)
{
    const int t  = threadIdx.x;
    const int qd = t & 255;
    const int sl = t >> 8;
    const int per = nblk >> 2;
    const float4* p4 = (const float4*)part;

    float4 a0 = make_float4(0.f, 0.f, 0.f, 0.f), a1 = a0;
    const int k0 = sl * per;
    #pragma unroll 2
    for (int k = 0; k < per; k += 2) {
        float4 p0 = p4[(size_t)((k0 + k)     * BB + b) * 256 + qd];
        float4 p1 = p4[(size_t)((k0 + k + 1) * BB + b) * 256 + qd];
        a0.x += p0.x; a0.y += p0.y; a0.z += p0.z; a0.w += p0.w;
        a1.x += p1.x; a1.y += p1.y; a1.z += p1.z; a1.w += p1.w;
    }
    a0.x += a1.x; a0.y += a1.y; a0.z += a1.z; a0.w += a1.w;

    redq[t] = a0;
    __syncthreads();

    float ss = 0.f;
    float4 x;
    if (t < 256) {
        float4 r0 = redq[qd], r1 = redq[256 + qd],
               r2 = redq[512 + qd], r3 = redq[768 + qd];
        float4 s;
        s.x = (r0.x + r1.x) + (r2.x + r3.x);
        s.y = (r0.y + r1.y) + (r2.y + r3.y);
        s.z = (r0.z + r1.z) + (r2.z + r3.z);
        s.w = (r0.w + r1.w) + (r2.w + r3.w);
        float4 bb = ((const float4*)bias)[qd];
        x.x = fmaf(s.x, scale, bb.x); x.y = fmaf(s.y, scale, bb.y);
        x.z = fmaf(s.z, scale, bb.z); x.w = fmaf(s.w, scale, bb.w);
        ss = x.x*x.x + x.y*x.y + x.z*x.z + x.w*x.w;
    }
    ss = wave_sum(ss);
    if ((t & 63) == 0) red2[t >> 6] = ss;
    __syncthreads();
    const float tot = (red2[0] + red2[1]) + (red2[2] + red2[3]);

    if (t < 256) {
        const float n = sqrtf(tot);
        const float f = tot / ((1.f + tot) * (n + EPSF));
        float4 vo;
        vo.x = x.x * f; vo.y = x.y * f; vo.z = x.z * f; vo.w = x.w * f;
        if (mode == 0) {
            ((float4*)(vbuf + b * OO))[qd] = vo;
        } else if (mode == 1) {
            float4 pv = ((const float4*)(vbuf + b * OO))[qd];
            pv.x += vo.x; pv.y += vo.y; pv.z += vo.z; pv.w += vo.w;
            ((float4*)(vbuf + b * OO))[qd] = pv;
        } else {
            ((float4*)(out + b * OO))[qd] = vo;
        }
    }
    __syncthreads();   // redq reused by caller's next phase
}

// ---------------- the mega kernel: 6 phases, 5 grid barriers -------------
__global__ __launch_bounds__(1024) void capsule_mega(
    const float* __restrict__ u, const float* __restrict__ w,
    const float* __restrict__ bias, float* __restrict__ out,
    float* __restrict__ part, float* __restrict__ vbuf, int* __restrict__ ctr)
{
    const int blk  = blockIdx.x;
    const int wv   = threadIdx.x >> 6;
    const int lane = threadIdx.x & 63;
    // stage mapping: 4096 wave-slots = 64 b x 64 iblk. 16 waves of a block
    // share one iblk (16x L1 reuse on w rows).
    const int gw   = blk * 16 + wv;
    const int b_s  = gw & 63;
    const int ib_s = gw >> 6;

    __shared__ float4 redq[1024];   // 16 KB
    __shared__ float  red2[16];

    // P1: gemm partials
    gemm_wave<MIPB>(u, w, part, b_s, ib_s, lane);
    gbar(ctr + 0);
    // P2: v1 = squash((u@w)/O + bias)
    if (blk < BB)
        reduce_block(part, bias, vbuf, out, 1.0f / (float)OO, 0, MIBLKS,
                     blk, redq, red2);
    gbar(ctr + 1);
    // P3: stage A partials (softmax vs v1)
    stage_wave<MIPB>(u, w, vbuf, part, b_s, ib_s, lane);
    gbar(ctr + 2);
    // P4: vsum = v1 + squash(s2 + bias)
    if (blk < BB)
        reduce_block(part, bias, vbuf, out, 1.0f, 1, MIBLKS, blk, redq, red2);
    gbar(ctr + 3);
    // P5: stage B partials (softmax vs vsum)
    stage_wave<MIPB>(u, w, vbuf, part, b_s, ib_s, lane);
    gbar(ctr + 4);
    // P6: out = squash(s3 + bias)
    if (blk < BB)
        reduce_block(part, bias, vbuf, out, 1.0f, 2, MIBLKS, blk, redq, red2);
}

// ---------------- fallback multi-kernel path (small workspace) -----------
#define FIBLKS 8
#define FIPB (II / FIBLKS)

__global__ __launch_bounds__(256) void gemm_fb(
    const float* __restrict__ u, const float* __restrict__ w,
    float* __restrict__ part)
{
    const int bg = blockIdx.x / FIBLKS, iblk = blockIdx.x % FIBLKS;
    const int wave = threadIdx.x >> 6, lane = threadIdx.x & 63;
    gemm_wave<FIPB>(u, w, part, bg * 4 + wave, iblk, lane);
}
__global__ __launch_bounds__(256) void stage_fb(
    const float* __restrict__ u, const float* __restrict__ w,
    const float* __restrict__ v, float* __restrict__ part)
{
    const int bg = blockIdx.x / FIBLKS, iblk = blockIdx.x % FIBLKS;
    const int wave = threadIdx.x >> 6, lane = threadIdx.x & 63;
    stage_wave<FIPB>(u, w, v, part, bg * 4 + wave, iblk, lane);
}
__global__ __launch_bounds__(1024) void reduce_fb(
    const float* __restrict__ part, const float* __restrict__ bias,
    float* __restrict__ vbuf, float* __restrict__ out,
    float scale, int mode, int nblk)
{
    __shared__ float4 redq[1024];
    __shared__ float  red2[16];
    reduce_block(part, bias, vbuf, out, scale, mode, nblk,
                 blockIdx.x, redq, red2);
}

extern "C" void kernel_launch(void* const* d_in, const int* in_sizes, int n_in,
                              void* d_out, int out_size, void* d_ws, size_t ws_size,
                              hipStream_t stream) {
    (void)in_sizes; (void)n_in; (void)out_size;
    const float* u    = (const float*)d_in[0];
    const float* w    = (const float*)d_in[1];
    const float* bias = (const float*)d_in[2];
    float* out = (float*)d_out;

    const size_t row = (size_t)BB * OO;                 // elements
    const size_t mega_need = (MIBLKS + 1) * row * 4 + 256;
    if (ws_size >= mega_need) {
        float* part = (float*)d_ws;
        float* vbuf = part + MIBLKS * row;
        int*   ctr  = (int*)(vbuf + row);
        hipMemsetAsync(ctr, 0, 8 * sizeof(int), stream);
        capsule_mega<<<dim3(NBLK), dim3(1024), 0, stream>>>(
            u, w, bias, out, part, vbuf, ctr);
    } else {
        float* part = (float*)d_ws;
        float* vbuf = part + FIBLKS * row;
        dim3 g((BB / 4) * FIBLKS), blk(256), rblk(1024);
        gemm_fb<<<g, blk, 0, stream>>>(u, w, part);
        reduce_fb<<<dim3(BB), rblk, 0, stream>>>(part, bias, vbuf, out,
                                                 1.0f / (float)OO, 0, FIBLKS);
        stage_fb<<<g, blk, 0, stream>>>(u, w, vbuf, part);
        reduce_fb<<<dim3(BB), rblk, 0, stream>>>(part, bias, vbuf, out,
                                                 1.0f, 1, FIBLKS);
        stage_fb<<<g, blk, 0, stream>>>(u, w, vbuf, part);
        reduce_fb<<<dim3(BB), rblk, 0, stream>>>(part, bias, vbuf, out,
                                                 1.0f, 2, FIBLKS);
    }
}